// Round 8
// baseline (3289.399 us; speedup 1.0000x reference)
//
#include <hip/hip_runtime.h>

typedef unsigned int u32;
typedef unsigned long long u64;

// coordinates (B=8, N=8192, 3) f32, features (B=8, N=8192, C=128) f32
// out: coords (B, M=2048, 3) ++ features (B, M, C=128), flat f32
#define BB 8
#define NN 8192
#define MM 2048
#define KK 32
#define CC 128

#define FPS_T 512           // threads per FPS workgroup (8 waves)
#define FPS_P 16            // points per thread (sorted contiguous run)
#define NCELL 4096          // 16^3 Morton cells

// conservative margins: 2^-18 dwarfs the <=10*2^-24 accumulated rn error
#define C_DOWN 0.9999961853027344f   // 1 - 2^-18
#define C_UP   1.0000038146972656f   // 1 + 2^-18

// ---------------------------------------------------------------------------
// DPP helpers (HW-proven rounds 5/7): full-wave reduce valid in lane 63;
// inclusive prefix-scan for the counting sort.
// ---------------------------------------------------------------------------
template <int Ctrl, int RowMask>
__device__ __forceinline__ int dpp_mov(int x) {
  return __builtin_amdgcn_update_dpp(x, x, Ctrl, RowMask, 0xf, false);
}
template <int Ctrl, int RowMask>
__device__ __forceinline__ u32 dpp_scan_add(u32 x) {
  return x + (u32)__builtin_amdgcn_update_dpp(0, (int)x, Ctrl, RowMask, 0xf, false);
}

__device__ __forceinline__ float wave_max63(float v) {
  v = fmaxf(v, __int_as_float(dpp_mov<0x111, 0xf>(__float_as_int(v))));
  v = fmaxf(v, __int_as_float(dpp_mov<0x112, 0xf>(__float_as_int(v))));
  v = fmaxf(v, __int_as_float(dpp_mov<0x114, 0xf>(__float_as_int(v))));
  v = fmaxf(v, __int_as_float(dpp_mov<0x118, 0xf>(__float_as_int(v))));
  v = fmaxf(v, __int_as_float(dpp_mov<0x142, 0xa>(__float_as_int(v))));
  v = fmaxf(v, __int_as_float(dpp_mov<0x143, 0xc>(__float_as_int(v))));
  return v;
}
__device__ __forceinline__ float wave_min63f(float v) {
  v = fminf(v, __int_as_float(dpp_mov<0x111, 0xf>(__float_as_int(v))));
  v = fminf(v, __int_as_float(dpp_mov<0x112, 0xf>(__float_as_int(v))));
  v = fminf(v, __int_as_float(dpp_mov<0x114, 0xf>(__float_as_int(v))));
  v = fminf(v, __int_as_float(dpp_mov<0x118, 0xf>(__float_as_int(v))));
  v = fminf(v, __int_as_float(dpp_mov<0x142, 0xa>(__float_as_int(v))));
  v = fminf(v, __int_as_float(dpp_mov<0x143, 0xc>(__float_as_int(v))));
  return v;
}
__device__ __forceinline__ u32 wave_minu63(u32 v) {
  u32 o;
  o = (u32)dpp_mov<0x111, 0xf>((int)v); v = o < v ? o : v;
  o = (u32)dpp_mov<0x112, 0xf>((int)v); v = o < v ? o : v;
  o = (u32)dpp_mov<0x114, 0xf>((int)v); v = o < v ? o : v;
  o = (u32)dpp_mov<0x118, 0xf>((int)v); v = o < v ? o : v;
  o = (u32)dpp_mov<0x142, 0xa>((int)v); v = o < v ? o : v;
  o = (u32)dpp_mov<0x143, 0xc>((int)v); v = o < v ? o : v;
  return v;
}
__device__ __forceinline__ u32 wave_scan_incl(u32 x) {
  x = dpp_scan_add<0x111, 0xf>(x);
  x = dpp_scan_add<0x112, 0xf>(x);
  x = dpp_scan_add<0x114, 0xf>(x);
  x = dpp_scan_add<0x118, 0xf>(x);
  x = dpp_scan_add<0x142, 0xa>(x);
  x = dpp_scan_add<0x143, 0xc>(x);
  return x;
}
__device__ __forceinline__ float rl63(float v) {  // lane63 -> uniform SGPR
  return __uint_as_float((u32)__builtin_amdgcn_readlane(__float_as_int(v), 63));
}

// 16^3 Morton cell over [-6,6]^3 (clustering quality only, not correctness)
__device__ __forceinline__ u32 spread4(u32 a) {
  return (a & 1u) | ((a & 2u) << 2) | ((a & 4u) << 4) | ((a & 8u) << 6);
}
__device__ __forceinline__ u32 cell_of(float x, float y, float z) {
  const u32 qx = (u32)(int)fminf(fmaxf((x + 6.0f) * 1.3333334f, 0.0f), 15.0f);
  const u32 qy = (u32)(int)fminf(fmaxf((y + 6.0f) * 1.3333334f, 0.0f), 15.0f);
  const u32 qz = (u32)(int)fminf(fmaxf((z + 6.0f) * 1.3333334f, 0.0f), 15.0f);
  return spread4(qx) | (spread4(qy) << 1) | (spread4(qz) << 2);
}

// ---------------------------------------------------------------------------
// FPS with exact spatial pruning.
//  - one-time LDS counting sort by Morton cell -> thread owns 16 tight points
//  - skip test (wave then thread): margined lower bound on new d2 vs cached
//    max(d2m) proves min-update is a no-op -> state stays bit-identical
//  - winner: gmax reduce; qualify iff __fsqrt_rn(d2m)==s (reference exact);
//    min ORIGINAL index tie-break; centroid via uniform LDS read.
// ---------------------------------------------------------------------------
__global__ __launch_bounds__(FPS_T, 1)
void fps_kernel(const float* __restrict__ coords, float* __restrict__ out_coords) {
  const int b = blockIdx.x, t = threadIdx.x, w = t >> 6, lane = t & 63;
  const float* cb = coords + (size_t)b * NN * 3;

  __shared__ float s_x[NN], s_y[NN], s_z[NN];   // 96 KB, ORIGINAL point order
  __shared__ u32 s_sidx[NN];                    // 32 KB sorted original idx
  __shared__ u32 s_hist[NCELL];                 // 16 KB
  __shared__ float s_gpart[FPS_T / 64];
  __shared__ u32 s_ipart[FPS_T / 64];
  __shared__ u32 s_wsum[FPS_T / 64];

  // --- load (coalesced strided), stage, histogram ---
  u32 cell[FPS_P];
  {
    float lx[FPS_P], ly[FPS_P], lz[FPS_P];
#pragma unroll
    for (int j = 0; j < FPS_P; ++j) {
      const int p = t + j * FPS_T;
      lx[j] = cb[p * 3 + 0]; ly[j] = cb[p * 3 + 1]; lz[j] = cb[p * 3 + 2];
      s_x[p] = lx[j]; s_y[p] = ly[j]; s_z[p] = lz[j];
    }
#pragma unroll
    for (int i = 0; i < NCELL / FPS_T; ++i) s_hist[t + i * FPS_T] = 0u;
    __syncthreads();
#pragma unroll
    for (int j = 0; j < FPS_P; ++j) {
      cell[j] = cell_of(lx[j], ly[j], lz[j]);
      atomicAdd(&s_hist[cell[j]], 1u);
    }
  }
  __syncthreads();

  // --- exclusive prefix over 4096 bins (8 bins/thread) ---
  {
    u32 h[8], ls = 0;
#pragma unroll
    for (int i = 0; i < 8; ++i) { h[i] = s_hist[t * 8 + i]; ls += h[i]; }
    const u32 incl = wave_scan_incl(ls);
    if (lane == 63) s_wsum[w] = incl;
    __syncthreads();
    u32 base = 0;
#pragma unroll
    for (int w2 = 0; w2 < FPS_T / 64; ++w2) base += (w2 < w) ? s_wsum[w2] : 0u;
    u32 run = base + incl - ls;
#pragma unroll
    for (int i = 0; i < 8; ++i) { const u32 hv = h[i]; s_hist[t * 8 + i] = run; run += hv; }
  }
  __syncthreads();

  // --- scatter (intra-cell order nondeterministic; values unaffected) ---
#pragma unroll
  for (int j = 0; j < FPS_P; ++j) {
    const u32 pos = atomicAdd(&s_hist[cell[j]], 1u);
    s_sidx[pos] = (u32)(t + j * FPS_T);
  }
  __syncthreads();

  // --- re-own sorted run; thread bounding sphere ---
  float x[FPS_P], y[FPS_P], z[FPS_P], d2m[FPS_P];
  u32 idx[FPS_P];
  float ccx, ccy, ccz, Rup;
  {
    float sx = 0.f, sy = 0.f, sz = 0.f;
#pragma unroll
    for (int j = 0; j < FPS_P; ++j) {
      idx[j] = s_sidx[t * FPS_P + j];
      x[j] = s_x[idx[j]]; y[j] = s_y[idx[j]]; z[j] = s_z[idx[j]];
      d2m[j] = 1e20f;  // sqrt-space 1e10 == d2-space 1e20
      sx += x[j]; sy += y[j]; sz += z[j];
    }
    ccx = sx * 0.0625f; ccy = sy * 0.0625f; ccz = sz * 0.0625f;
    float r2 = 0.f;
#pragma unroll
    for (int j = 0; j < FPS_P; ++j) {
      const float dx = x[j] - ccx, dy = y[j] - ccy, dz = z[j] - ccz;
      r2 = fmaxf(r2, dx * dx + dy * dy + dz * dz);
    }
    Rup = __fsqrt_rn(r2) * C_UP + 1e-30f;
  }

  // --- wave bounding sphere (uniform via lane63 + readlane) ---
  float wcx, wcy, wcz, wR;
  {
    const float lx = rl63(wave_min63f(ccx - Rup)), hx = rl63(wave_max63(ccx + Rup));
    const float ly = rl63(wave_min63f(ccy - Rup)), hy = rl63(wave_max63(ccy + Rup));
    const float lz = rl63(wave_min63f(ccz - Rup)), hz = rl63(wave_max63(ccz + Rup));
    wcx = (lx + hx) * 0.5f; wcy = (ly + hy) * 0.5f; wcz = (lz + hz) * 0.5f;
    const float ddx = ccx - wcx, ddy = ccy - wcy, ddz = ccz - wcz;
    const float dr = __fsqrt_rn(ddx * ddx + ddy * ddy + ddz * ddz) * C_UP + Rup;
    wR = rl63(wave_max63(dr)) * C_UP + 1e-30f;
  }

  if (t == 0) {
    out_coords[(size_t)(b * MM) * 3 + 0] = cb[0];
    out_coords[(size_t)(b * MM) * 3 + 1] = cb[1];
    out_coords[(size_t)(b * MM) * 3 + 2] = cb[2];
  }
  float cx = cb[0], cy = cb[1], cz = cb[2];
  float bestv = 1e20f;   // exact max of my d2m (cached)
  float wbest = 1e20f;   // exact max over wave's d2m (uniform, cached)

  for (int it = 1; it < MM; ++it) {
    // --- wave-level exact skip test (uniform) ---
    const float wdx = __fsub_rn(wcx, cx), wdy = __fsub_rn(wcy, cy), wdz = __fsub_rn(wcz, cz);
    const float wd2 = __fadd_rn(__fadd_rn(__fmul_rn(wdx, wdx), __fmul_rn(wdy, wdy)),
                                __fmul_rn(wdz, wdz));
    const float wlc = __fsub_rn(__fmul_rn(__fsqrt_rn(wd2), C_DOWN), wR);
    const bool wskip = (wlc > 0.0f) &&
                       (__fmul_rn(__fmul_rn(wlc, wlc), C_DOWN) >= wbest);
    if (!wskip) {
      // --- thread-level skip test ---
      const float tdx = __fsub_rn(ccx, cx), tdy = __fsub_rn(ccy, cy), tdz = __fsub_rn(ccz, cz);
      const float td2 = __fadd_rn(__fadd_rn(__fmul_rn(tdx, tdx), __fmul_rn(tdy, tdy)),
                                  __fmul_rn(tdz, tdz));
      const float tlc = __fsub_rn(__fmul_rn(__fsqrt_rn(td2), C_DOWN), Rup);
      const bool tskip = (tlc > 0.0f) &&
                         (__fmul_rn(__fmul_rn(tlc, tlc), C_DOWN) >= bestv);
      if (!tskip) {
        float bv = -1.0f;
#pragma unroll
        for (int j = 0; j < FPS_P; ++j) {  // verbatim round-5 exact math
          const float dx = __fsub_rn(x[j], cx);
          const float dy = __fsub_rn(y[j], cy);
          const float dz = __fsub_rn(z[j], cz);
          const float d2 = __fadd_rn(__fadd_rn(__fmul_rn(dx, dx), __fmul_rn(dy, dy)),
                                     __fmul_rn(dz, dz));
          const float nd = fminf(d2m[j], d2);
          d2m[j] = nd;
          bv = fmaxf(bv, nd);
        }
        bestv = bv;
      }
      const float wv = wave_max63(bestv);
      if (lane == 63) s_gpart[w] = wv;
      wbest = rl63(wv);
    } else {
      if (lane == 63) s_gpart[w] = wbest;  // unchanged wave max
    }
    __syncthreads();  // A
    float gmax = s_gpart[0];
#pragma unroll
    for (int w2 = 1; w2 < FPS_T / 64; ++w2) gmax = fmaxf(gmax, s_gpart[w2]);
    const float s = __fsqrt_rn(gmax);  // == reference max dist

    // --- qualify iff sqrt_rn(d2m)==s (reference-exact); min ORIGINAL idx ---
    u32 mi = 0xFFFFFFFFu;
    if (__fsqrt_rn(bestv) == s) {
#pragma unroll
      for (int j = 0; j < FPS_P; ++j)
        if (__fsqrt_rn(d2m[j]) == s && idx[j] < mi) mi = idx[j];
    }
    const u32 wi = wave_minu63(mi);
    if (lane == 63) s_ipart[w] = wi;
    __syncthreads();  // B
    u32 widx = s_ipart[0];
#pragma unroll
    for (int w2 = 1; w2 < FPS_T / 64; ++w2)
      widx = s_ipart[w2] < widx ? s_ipart[w2] : widx;

    // --- centroid broadcast: uniform-address LDS reads (original order) ---
    cx = s_x[widx]; cy = s_y[widx]; cz = s_z[widx];
    if (t == (it & (FPS_T - 1))) {
      float* oc = out_coords + ((size_t)b * MM + it) * 3;
      oc[0] = cx; oc[1] = cy; oc[2] = cz;
    }
  }
}

// ---------------------------------------------------------------------------
// KNN top-32 + feature mean via EXACT radix-select (round-7 verbatim, proven:
// ~320 us). Set of 32 smallest 45-bit keys (flipped-d2<<13 | idx) == lax.top_k.
// ---------------------------------------------------------------------------
__global__ __launch_bounds__(256, 4)
void knn_mean_kernel(const float* __restrict__ coords,
                     const float* __restrict__ feats,
                     const float* __restrict__ out_coords,
                     float* __restrict__ out_feats) {
  const int q = blockIdx.x;   // b*MM + m
  const int b = q >> 11;
  const int t = threadIdx.x;
  const float* cb = coords + (size_t)b * NN * 3;

  const float cx = out_coords[(size_t)q * 3 + 0];
  const float cy = out_coords[(size_t)q * 3 + 1];
  const float cz = out_coords[(size_t)q * 3 + 2];
  const float c2 = __fadd_rn(__fadd_rn(__fmul_rn(cx, cx), __fmul_rn(cy, cy)),
                             __fmul_rn(cz, cz));

  u32 D[32];
  const float* tb = cb + t * 96;
#pragma unroll
  for (int ch = 0; ch < 8; ++ch) {
    const float4 q0 = *(const float4*)(tb + ch * 12 + 0);
    const float4 q1 = *(const float4*)(tb + ch * 12 + 4);
    const float4 q2 = *(const float4*)(tb + ch * 12 + 8);
    const float pxs[4] = {q0.x, q0.w, q1.z, q2.y};
    const float pys[4] = {q0.y, q1.x, q1.w, q2.z};
    const float pzs[4] = {q0.z, q1.y, q2.x, q2.w};
#pragma unroll
    for (int kk = 0; kk < 4; ++kk) {
      const int j = ch * 4 + kk;
      const float px = pxs[kk], py = pys[kk], pz = pzs[kk];
      const float p2 = __fadd_rn(__fadd_rn(__fmul_rn(px, px), __fmul_rn(py, py)),
                                 __fmul_rn(pz, pz));
      const float dot = __fmaf_rn(cz, pz, __fmaf_rn(cy, py, __fmul_rn(cx, px)));
      const float d2 = __fsub_rn(__fadd_rn(c2, p2), __fadd_rn(dot, dot));
      u32 ub = __float_as_uint(d2);
      ub ^= (((u32)((int)ub >> 31)) | 0x80000000u);
      D[j] = ub;
    }
  }

  __shared__ u32 s_hist[4096];
  __shared__ u32 s_wsum[4];
  __shared__ u32 s_bin, s_r, s_full;
  __shared__ u32 s_cnt;
  __shared__ int s_nbr[KK];
  __shared__ float s_sum[CC];

  const int w = t >> 6;
  u64 hi = 0;
  u32 k_rem = KK;
  u64 thr = 0;
  bool done = false;

  constexpr int SHIFT[4] = {33, 22, 11, 0};
  constexpr int SBITS[4] = {45, 33, 22, 11};

#pragma unroll
  for (int p = 0; p < 4; ++p) {
    if (!done) {
      const uint4 z4 = {0u, 0u, 0u, 0u};
#pragma unroll
      for (int i = 0; i < 4; ++i) *(uint4*)&s_hist[t * 16 + i * 4] = z4;
      __syncthreads();

#pragma unroll
      for (int j = 0; j < 32; ++j) {
        const u64 key = ((u64)D[j] << 13) | (u32)(t * 32 + j);
        if ((key >> SBITS[p]) == hi)
          atomicAdd(&s_hist[(u32)(key >> SHIFT[p]) & 4095u], 1u);
      }
      __syncthreads();

      const uint4 h0 = *(const uint4*)&s_hist[t * 16 + 0];
      const uint4 h1 = *(const uint4*)&s_hist[t * 16 + 4];
      const uint4 h2 = *(const uint4*)&s_hist[t * 16 + 8];
      const uint4 h3 = *(const uint4*)&s_hist[t * 16 + 12];
      const u32 ls = h0.x + h0.y + h0.z + h0.w + h1.x + h1.y + h1.z + h1.w +
                     h2.x + h2.y + h2.z + h2.w + h3.x + h3.y + h3.z + h3.w;
      const u32 incl = wave_scan_incl(ls);
      if ((t & 63) == 63) s_wsum[w] = incl;
      __syncthreads();
      u32 base = 0;
      if (w > 0) base += s_wsum[0];
      if (w > 1) base += s_wsum[1];
      if (w > 2) base += s_wsum[2];
      const u32 pre_grp = base + incl - ls;

      if (pre_grp < k_rem && k_rem <= pre_grp + ls) {
        const u32 hh[16] = {h0.x, h0.y, h0.z, h0.w, h1.x, h1.y, h1.z, h1.w,
                            h2.x, h2.y, h2.z, h2.w, h3.x, h3.y, h3.z, h3.w};
        u32 c = pre_grp;
#pragma unroll
        for (int i = 0; i < 16; ++i) {
          const u32 h = hh[i];
          if (k_rem > c && k_rem <= c + h) {
            s_bin = (u32)(t * 16 + i);
            s_r = k_rem - c;
            s_full = (k_rem - c == h) ? 1u : 0u;
          }
          c += h;
        }
      }
      __syncthreads();

      const u32 bin = s_bin;
      const u32 r = s_r;
      const u32 fullf = s_full;
      hi = (hi << (SBITS[p] - SHIFT[p])) | bin;
      if (fullf) {
        thr = (SHIFT[p] > 0) ? ((hi << SHIFT[p]) | ((1ULL << SHIFT[p]) - 1ULL))
                             : hi;
        done = true;
      } else {
        k_rem = r;
      }
    }
  }

  if (t == 0) s_cnt = 0;
  __syncthreads();
#pragma unroll
  for (int j = 0; j < 32; ++j) {
    const u64 key = ((u64)D[j] << 13) | (u32)(t * 32 + j);
    if (key <= thr) {
      const u32 pos = atomicAdd(&s_cnt, 1u);
      s_nbr[pos] = t * 32 + j;
    }
  }
  __syncthreads();

  const int c = t & (CC - 1);
  const int half = t >> 7;
  const float* fb = feats + (size_t)b * NN * CC;
  float s = 0.0f;
#pragma unroll
  for (int k = 0; k < 16; ++k) {
    const int p = s_nbr[half * 16 + k];
    s = __fadd_rn(s, fb[(size_t)p * CC + c]);
  }
  if (half == 1) s_sum[c] = s;
  __syncthreads();
  if (half == 0) {
    const float tot = __fadd_rn(s, s_sum[c]);
    out_feats[(size_t)q * CC + c] = tot * 0.03125f;
  }
}

// ---------------------------------------------------------------------------
extern "C" void kernel_launch(void* const* d_in, const int* in_sizes, int n_in,
                              void* d_out, int out_size, void* d_ws, size_t ws_size,
                              hipStream_t stream) {
  const float* coords = (const float*)d_in[0];
  const float* feats  = (const float*)d_in[1];
  float* out_coords = (float*)d_out;                        // B*M*3
  float* out_feats  = (float*)d_out + (size_t)BB * MM * 3;  // B*M*C

  fps_kernel<<<BB, FPS_T, 0, stream>>>(coords, out_coords);
  knn_mean_kernel<<<BB * MM, 256, 0, stream>>>(coords, feats, out_coords,
                                               out_feats);
}

// Round 9
// 2325.728 us; speedup vs baseline: 1.4144x; 1.4144x over previous
//
#include <hip/hip_runtime.h>

typedef unsigned int u32;
typedef unsigned long long u64;
typedef float f32x2 __attribute__((ext_vector_type(2)));

// coordinates (B=8, N=8192, 3) f32, features (B=8, N=8192, C=128) f32
// out: coords (B, M=2048, 3) ++ features (B, M, C=128), flat f32
#define BB 8
#define NN 8192
#define MM 2048
#define KK 32
#define CC 128

#define FPS_T 512        // threads per FPS workgroup (8 waves)
#define FPS_PAIRS 8      // f32x2 pairs per thread (16 points)

// ---------------------------------------------------------------------------
// DPP helpers (HW-proven round 5): full-wave reduce valid in lane 63;
// inclusive prefix-scan for the radix histogram.
// ---------------------------------------------------------------------------
template <int Ctrl, int RowMask>
__device__ __forceinline__ int dpp_mov(int x) {
  return __builtin_amdgcn_update_dpp(x, x, Ctrl, RowMask, 0xf, false);
}
template <int Ctrl, int RowMask>
__device__ __forceinline__ u32 dpp_scan_add(u32 x) {
  return x + (u32)__builtin_amdgcn_update_dpp(0, (int)x, Ctrl, RowMask, 0xf, false);
}

__device__ __forceinline__ float wave_max63(float v) {
  v = fmaxf(v, __int_as_float(dpp_mov<0x111, 0xf>(__float_as_int(v))));  // shr1
  v = fmaxf(v, __int_as_float(dpp_mov<0x112, 0xf>(__float_as_int(v))));  // shr2
  v = fmaxf(v, __int_as_float(dpp_mov<0x114, 0xf>(__float_as_int(v))));  // shr4
  v = fmaxf(v, __int_as_float(dpp_mov<0x118, 0xf>(__float_as_int(v))));  // shr8
  v = fmaxf(v, __int_as_float(dpp_mov<0x142, 0xa>(__float_as_int(v))));  // bc15
  v = fmaxf(v, __int_as_float(dpp_mov<0x143, 0xc>(__float_as_int(v))));  // bc31
  return v;
}

__device__ __forceinline__ u32 wave_minu63(u32 v) {
  u32 o;
  o = (u32)dpp_mov<0x111, 0xf>((int)v); v = o < v ? o : v;
  o = (u32)dpp_mov<0x112, 0xf>((int)v); v = o < v ? o : v;
  o = (u32)dpp_mov<0x114, 0xf>((int)v); v = o < v ? o : v;
  o = (u32)dpp_mov<0x118, 0xf>((int)v); v = o < v ? o : v;
  o = (u32)dpp_mov<0x142, 0xa>((int)v); v = o < v ? o : v;
  o = (u32)dpp_mov<0x143, 0xc>((int)v); v = o < v ? o : v;
  return v;
}

__device__ __forceinline__ u32 wave_scan_incl(u32 x) {
  x = dpp_scan_add<0x111, 0xf>(x);
  x = dpp_scan_add<0x112, 0xf>(x);
  x = dpp_scan_add<0x114, 0xf>(x);
  x = dpp_scan_add<0x118, 0xf>(x);
  x = dpp_scan_add<0x142, 0xa>(x);
  x = dpp_scan_add<0x143, 0xc>(x);
  return x;
}

// ---------------------------------------------------------------------------
// FPS: round-5 structure (best measured: 2072 us) with the update loop in
// compiler-generated packed f32 (v_pk_*). contract(off) forbids mul+add
// fusion, so per-element arithmetic == __fsub_rn/__fmul_rn/__fadd_rn of the
// reference. d2-space argmax + exact sqrt-space tie repair; 2 barriers/iter,
// 0 atomics; centroid broadcast via uniform-address LDS read.
// ---------------------------------------------------------------------------
__global__ __launch_bounds__(FPS_T, 1)
void fps_kernel(const float* __restrict__ coords, float* __restrict__ out_coords) {
#pragma clang fp contract(off)
  const int b = blockIdx.x;
  const int t = threadIdx.x;
  const float* cb = coords + (size_t)b * NN * 3;

  __shared__ float s_x[NN], s_y[NN], s_z[NN];  // 96 KB coords mirror
  __shared__ float s_gpart[FPS_T / 64];
  __shared__ u32 s_ipart[FPS_T / 64];

  f32x2 x[FPS_PAIRS], y[FPS_PAIRS], z[FPS_PAIRS], d2m[FPS_PAIRS];
#pragma unroll
  for (int k = 0; k < FPS_PAIRS; ++k) {
    const int p0 = t + (2 * k) * FPS_T;
    const int p1 = t + (2 * k + 1) * FPS_T;
    x[k].x = cb[p0 * 3 + 0]; x[k].y = cb[p1 * 3 + 0];
    y[k].x = cb[p0 * 3 + 1]; y[k].y = cb[p1 * 3 + 1];
    z[k].x = cb[p0 * 3 + 2]; z[k].y = cb[p1 * 3 + 2];
    d2m[k].x = 1e20f; d2m[k].y = 1e20f;  // sqrt-space 1e10 == d2-space 1e20
    s_x[p0] = x[k].x; s_x[p1] = x[k].y;
    s_y[p0] = y[k].x; s_y[p1] = y[k].y;
    s_z[p0] = z[k].x; s_z[p1] = z[k].y;
  }
  // staging writes ordered before first s_x[widx] read by barrier A below

  if (t == 0) {
    out_coords[(size_t)(b * MM) * 3 + 0] = cb[0];
    out_coords[(size_t)(b * MM) * 3 + 1] = cb[1];
    out_coords[(size_t)(b * MM) * 3 + 2] = cb[2];
  }
  float cx = cb[0], cy = cb[1], cz = cb[2];

  for (int it = 1; it < MM; ++it) {
    // --- update squared dists (packed, unfused => exact); local max ---
    const f32x2 vcx = {cx, cx}, vcy = {cy, cy}, vcz = {cz, cz};
    f32x2 bv = {-1.0f, -1.0f};
#pragma unroll
    for (int k = 0; k < FPS_PAIRS; ++k) {
      const f32x2 dx = x[k] - vcx;                 // v_pk_add_f32 (neg mod)
      const f32x2 dy = y[k] - vcy;
      const f32x2 dz = z[k] - vcz;
      const f32x2 d2 = (dx * dx + dy * dy) + dz * dz;  // pk_mul/add, no fma
      const f32x2 nd = __builtin_elementwise_min(d2m[k], d2);  // v_pk_min_f32
      d2m[k] = nd;
      bv = __builtin_elementwise_max(bv, nd);                  // v_pk_max_f32
    }
    const float bestv = fmaxf(bv.x, bv.y);

    // --- phase 1: global max via DPP + one LDS/barrier hop ---
    const float wv = wave_max63(bestv);
    if ((t & 63) == 63) s_gpart[t >> 6] = wv;
    __syncthreads();  // A
    float gmax = s_gpart[0];
#pragma unroll
    for (int w = 1; w < FPS_T / 64; ++w) gmax = fmaxf(gmax, s_gpart[w]);

    // --- exact sqrt-space tie threshold (verbatim rounds 4-7) ---
    float lo_f;
    if (!(gmax > 0.0f)) {
      lo_f = 0.0f;
    } else {
      const float s = __fsqrt_rn(gmax);                        // == ref max dist
      const float sp = __int_as_float(__float_as_int(s) - 1);  // nextafter down
      const double mid = 0.5 * ((double)s + (double)sp);       // exact
      const double lod = mid * mid;                            // exact
      float c = (float)lod;
      if ((double)c < lod) c = __int_as_float(__float_as_int(c) + 1);  // ceil
      lo_f = c;  // d2 >= lo_f  <=>  sqrt_rn(d2) == s   (for d2 <= gmax)
    }

    // --- phase 2: min index among d2m >= lo_f (execz-skipped for most) ---
    u32 mi = 0xFFFFFFFFu;
    if (bestv >= lo_f) {
#pragma unroll
      for (int k = 0; k < FPS_PAIRS; ++k) {
        const u32 p0 = (u32)(t + (2 * k) * FPS_T);
        const u32 p1 = (u32)(t + (2 * k + 1) * FPS_T);
        if (d2m[k].x >= lo_f && p0 < mi) mi = p0;
        if (d2m[k].y >= lo_f && p1 < mi) mi = p1;
      }
    }
    const u32 wi = wave_minu63(mi);
    if ((t & 63) == 63) s_ipart[t >> 6] = wi;
    __syncthreads();  // B
    u32 widx = s_ipart[0];
#pragma unroll
    for (int w = 1; w < FPS_T / 64; ++w)
      widx = s_ipart[w] < widx ? s_ipart[w] : widx;

    // --- centroid broadcast: uniform-address LDS read ---
    cx = s_x[widx]; cy = s_y[widx]; cz = s_z[widx];
    if (t == (it & (FPS_T - 1))) {  // off-critical-path output store
      float* oc = out_coords + ((size_t)b * MM + it) * 3;
      oc[0] = cx; oc[1] = cy; oc[2] = cz;
    }
  }
}

// ---------------------------------------------------------------------------
// KNN top-32 + feature mean via EXACT radix-select (round-7 verbatim, proven).
// Set of 32 smallest 45-bit keys (flipped-d2<<13 | idx) == lax.top_k set.
// ---------------------------------------------------------------------------
__global__ __launch_bounds__(256, 4)
void knn_mean_kernel(const float* __restrict__ coords,
                     const float* __restrict__ feats,
                     const float* __restrict__ out_coords,
                     float* __restrict__ out_feats) {
  const int q = blockIdx.x;   // b*MM + m
  const int b = q >> 11;
  const int t = threadIdx.x;
  const float* cb = coords + (size_t)b * NN * 3;

  const float cx = out_coords[(size_t)q * 3 + 0];
  const float cy = out_coords[(size_t)q * 3 + 1];
  const float cz = out_coords[(size_t)q * 3 + 2];
  const float c2 = __fadd_rn(__fadd_rn(__fmul_rn(cx, cx), __fmul_rn(cy, cy)),
                             __fmul_rn(cz, cz));

  u32 D[32];
  const float* tb = cb + t * 96;
#pragma unroll
  for (int ch = 0; ch < 8; ++ch) {
    const float4 q0 = *(const float4*)(tb + ch * 12 + 0);
    const float4 q1 = *(const float4*)(tb + ch * 12 + 4);
    const float4 q2 = *(const float4*)(tb + ch * 12 + 8);
    const float pxs[4] = {q0.x, q0.w, q1.z, q2.y};
    const float pys[4] = {q0.y, q1.x, q1.w, q2.z};
    const float pzs[4] = {q0.z, q1.y, q2.x, q2.w};
#pragma unroll
    for (int kk = 0; kk < 4; ++kk) {
      const int j = ch * 4 + kk;
      const float px = pxs[kk], py = pys[kk], pz = pzs[kk];
      const float p2 = __fadd_rn(__fadd_rn(__fmul_rn(px, px), __fmul_rn(py, py)),
                                 __fmul_rn(pz, pz));
      const float dot = __fmaf_rn(cz, pz, __fmaf_rn(cy, py, __fmul_rn(cx, px)));
      const float d2 = __fsub_rn(__fadd_rn(c2, p2), __fadd_rn(dot, dot));
      u32 ub = __float_as_uint(d2);
      ub ^= (((u32)((int)ub >> 31)) | 0x80000000u);
      D[j] = ub;
    }
  }

  __shared__ u32 s_hist[4096];
  __shared__ u32 s_wsum[4];
  __shared__ u32 s_bin, s_r, s_full;
  __shared__ u32 s_cnt;
  __shared__ int s_nbr[KK];
  __shared__ float s_sum[CC];

  const int w = t >> 6;
  u64 hi = 0;
  u32 k_rem = KK;
  u64 thr = 0;
  bool done = false;

  constexpr int SHIFT[4] = {33, 22, 11, 0};
  constexpr int SBITS[4] = {45, 33, 22, 11};

#pragma unroll
  for (int p = 0; p < 4; ++p) {
    if (!done) {
      const uint4 z4 = {0u, 0u, 0u, 0u};
#pragma unroll
      for (int i = 0; i < 4; ++i) *(uint4*)&s_hist[t * 16 + i * 4] = z4;
      __syncthreads();

#pragma unroll
      for (int j = 0; j < 32; ++j) {
        const u64 key = ((u64)D[j] << 13) | (u32)(t * 32 + j);
        if ((key >> SBITS[p]) == hi)
          atomicAdd(&s_hist[(u32)(key >> SHIFT[p]) & 4095u], 1u);
      }
      __syncthreads();

      const uint4 h0 = *(const uint4*)&s_hist[t * 16 + 0];
      const uint4 h1 = *(const uint4*)&s_hist[t * 16 + 4];
      const uint4 h2 = *(const uint4*)&s_hist[t * 16 + 8];
      const uint4 h3 = *(const uint4*)&s_hist[t * 16 + 12];
      const u32 ls = h0.x + h0.y + h0.z + h0.w + h1.x + h1.y + h1.z + h1.w +
                     h2.x + h2.y + h2.z + h2.w + h3.x + h3.y + h3.z + h3.w;
      const u32 incl = wave_scan_incl(ls);
      if ((t & 63) == 63) s_wsum[w] = incl;
      __syncthreads();
      u32 base = 0;
      if (w > 0) base += s_wsum[0];
      if (w > 1) base += s_wsum[1];
      if (w > 2) base += s_wsum[2];
      const u32 pre_grp = base + incl - ls;

      if (pre_grp < k_rem && k_rem <= pre_grp + ls) {
        const u32 hh[16] = {h0.x, h0.y, h0.z, h0.w, h1.x, h1.y, h1.z, h1.w,
                            h2.x, h2.y, h2.z, h2.w, h3.x, h3.y, h3.z, h3.w};
        u32 c = pre_grp;
#pragma unroll
        for (int i = 0; i < 16; ++i) {
          const u32 h = hh[i];
          if (k_rem > c && k_rem <= c + h) {
            s_bin = (u32)(t * 16 + i);
            s_r = k_rem - c;
            s_full = (k_rem - c == h) ? 1u : 0u;
          }
          c += h;
        }
      }
      __syncthreads();

      const u32 bin = s_bin;
      const u32 r = s_r;
      const u32 fullf = s_full;
      hi = (hi << (SBITS[p] - SHIFT[p])) | bin;
      if (fullf) {
        thr = (SHIFT[p] > 0) ? ((hi << SHIFT[p]) | ((1ULL << SHIFT[p]) - 1ULL))
                             : hi;
        done = true;
      } else {
        k_rem = r;
      }
    }
  }

  if (t == 0) s_cnt = 0;
  __syncthreads();
#pragma unroll
  for (int j = 0; j < 32; ++j) {
    const u64 key = ((u64)D[j] << 13) | (u32)(t * 32 + j);
    if (key <= thr) {
      const u32 pos = atomicAdd(&s_cnt, 1u);
      s_nbr[pos] = t * 32 + j;
    }
  }
  __syncthreads();

  const int c = t & (CC - 1);
  const int half = t >> 7;
  const float* fb = feats + (size_t)b * NN * CC;
  float s = 0.0f;
#pragma unroll
  for (int k = 0; k < 16; ++k) {
    const int p = s_nbr[half * 16 + k];
    s = __fadd_rn(s, fb[(size_t)p * CC + c]);
  }
  if (half == 1) s_sum[c] = s;
  __syncthreads();
  if (half == 0) {
    const float tot = __fadd_rn(s, s_sum[c]);        // low16 + high16
    out_feats[(size_t)q * CC + c] = tot * 0.03125f;  // exact /32
  }
}

// ---------------------------------------------------------------------------
extern "C" void kernel_launch(void* const* d_in, const int* in_sizes, int n_in,
                              void* d_out, int out_size, void* d_ws, size_t ws_size,
                              hipStream_t stream) {
  const float* coords = (const float*)d_in[0];
  const float* feats  = (const float*)d_in[1];
  float* out_coords = (float*)d_out;                        // B*M*3
  float* out_feats  = (float*)d_out + (size_t)BB * MM * 3;  // B*M*C

  fps_kernel<<<BB, FPS_T, 0, stream>>>(coords, out_coords);
  knn_mean_kernel<<<BB * MM, 256, 0, stream>>>(coords, feats, out_coords,
                                               out_feats);
}